// Round 9
// baseline (439.981 us; speedup 1.0000x reference)
//
#include <hip/hip_runtime.h>
#include <hip/hip_bf16.h>
#include <math.h>

#define B_SZ   8192
#define S_SZ   16
#define D_SZ   128
#define HID_SZ 1024
#define NUMF_SZ 103
#define GCN_SZ 40
#define G_B    4                 // batch elements per block (64 rows)
#define NBLK   (B_SZ / G_B)      // 2048 encoder blocks
#define SBLK   512               // stats blocks appended AFTER encoder blocks
#define STRD   136               // LDS row stride (shorts), pad 8

typedef short bh8 __attribute__((ext_vector_type(8)));   // 8 bf16 (4 VGPRs)
typedef float fx4 __attribute__((ext_vector_type(4)));   // MFMA accumulator
typedef unsigned short us4 __attribute__((ext_vector_type(4))); // 4 bf16 (8B)

__device__ __forceinline__ fx4 mfma16(bh8 a, bh8 b, fx4 c) {
    return __builtin_amdgcn_mfma_f32_16x16x32_bf16(a, b, c, 0, 0, 0);
}

// fp32 -> bf16 bits via native conversion (RNE, 1 VALU op)
__device__ __forceinline__ unsigned short f2b(float f) {
    union { __hip_bfloat16 b; unsigned short u; } cv;
    cv.b = __float2bfloat16(f);
    return cv.u;
}
__device__ __forceinline__ float bu2f(unsigned short u) {
    return __uint_as_float(((unsigned)u) << 16);
}

// Weight swizzle (src-driven, coalesced reads, scatter 2B writes):
//   QKVO : [l][nt(8)][ks(4)][lane(64)][e(8)]
//   W1   : [l][nt(64)][ks(4)][lane][e]
//   W2   : [l][nt(8)][kt(32)][lane][e]
__global__ __launch_bounds__(256) void prep_weights(
    const float* __restrict__ Wq, const float* __restrict__ Wk,
    const float* __restrict__ Wv, const float* __restrict__ Wo,
    const float* __restrict__ W1, const float* __restrict__ W2,
    unsigned short* __restrict__ WswQ, unsigned short* __restrict__ WswK,
    unsigned short* __restrict__ WswV, unsigned short* __restrict__ WswO,
    unsigned short* __restrict__ Wsw1, unsigned short* __restrict__ Wsw2,
    float* __restrict__ PEt)
{
    int j = blockIdx.x * 256 + threadIdx.x;   // 0..262143
    if (j < 2048) {  // PE table [16][128]
        int s = j >> 7, c = j & 127;
        float expo = (float)((c >> 1) * 2) * (1.0f / 128.0f);
        float denom = powf(10000.0f, expo);
        float ang = (float)s / denom;
        PEt[j] = (c & 1) ? cosf(ang) : sinf(ang);
    }
    if (j < 2 * 16384) {   // QKVO: src [l][k=128][n=128]
        int r = j & 16383, l = j >> 14;
        int k = r >> 7, n = r & 127;
        int dst = (((l * 8 + (n >> 4)) * 4 + (k >> 5)) * 64 +
                   (((k >> 3) & 3) * 16 + (n & 15))) * 8 + (k & 7);
        WswQ[dst] = f2b(Wq[j]); WswK[dst] = f2b(Wk[j]);
        WswV[dst] = f2b(Wv[j]); WswO[dst] = f2b(Wo[j]);
    }
    {   // W1: src [l][k=128][n=1024]
        int l = j >> 17, r = j & 131071;
        int k = r >> 10, n = r & 1023;
        int dst = (((l * 64 + (n >> 4)) * 4 + (k >> 5)) * 64 +
                   (((k >> 3) & 3) * 16 + (n & 15))) * 8 + (k & 7);
        Wsw1[dst] = f2b(W1[j]);
    }
    {   // W2: src [l][k=1024][n=128]
        int l = j >> 17, r = j & 131071;
        int k = r >> 7, n = r & 127;
        int dst = (((l * 8 + (n >> 4)) * 32 + (k >> 5)) * 64 +
                   (((k >> 3) & 3) * 16 + (n & 15))) * 8 + (k & 7);
        Wsw2[dst] = f2b(W2[j]);
    }
}

// Mega kernel, 512-thread blocks (8 waves):
//   blocks [0, NBLK)        = encoder, 4 batch elements, 1 n-tile PER WAVE
//   blocks [NBLK, NBLK+SBLK) = BN-stats (+ last-block cvec) -- backfill tail.
// Same LDS / barriers / weight traffic as the 4-wave version, but 2 blocks/CU
// now hold 16 waves (4/SIMD) instead of 8 -> 2x latency hiding.
// launch_bounds(512,4): VGPR cap 128; per-wave live sets trimmed (1 n-tile,
// hfr reloaded per FF chunk) to stay under it without spilling.
__global__ __launch_bounds__(512, 4) void encoder_fused(
    const float* __restrict__ x, const float* __restrict__ gcn,
    const float* __restrict__ bq, const float* __restrict__ bk,
    const float* __restrict__ bv, const float* __restrict__ bo,
    const float* __restrict__ ln1g, const float* __restrict__ ln1b,
    const float* __restrict__ b1, const float* __restrict__ b2p,
    const float* __restrict__ ln2g, const float* __restrict__ ln2b,
    const float* __restrict__ Wf,
    const unsigned short* __restrict__ WswQ, const unsigned short* __restrict__ WswK,
    const unsigned short* __restrict__ WswV, const unsigned short* __restrict__ WswO,
    const unsigned short* __restrict__ Wsw1, const unsigned short* __restrict__ Wsw2,
    const float* __restrict__ PEt,
    const float* __restrict__ num, const float* __restrict__ Wn,
    const float* __restrict__ bnum,
    float* __restrict__ ssum, float* __restrict__ ssq,
    unsigned int* __restrict__ cnt,
    const float* __restrict__ bng, const float* __restrict__ bnb,
    const float* __restrict__ bfin, float* __restrict__ cvec,
    float* __restrict__ acc1)
{
    __shared__ unsigned short ACT[64][STRD];  // activations / LN2 output
    __shared__ unsigned short Qb[64][STRD];   // Q -> ctx -> FF1 chunk (even)
    __shared__ unsigned short Kb[64][STRD];   // K -> H (post-LN1)
    __shared__ unsigned short Vb[64][STRD];   // V^T (per-head) -> FF1 chunk (odd)
    __shared__ unsigned long long SCRU[512];  // 4KB union: Pb | LNp2 | redw
    __shared__ int lastf;

    unsigned short* Pb   = (unsigned short*)SCRU;  // [8][16][16] attn probs
    float2*         LNp2 = (float2*)SCRU;          // [64][8] per-row per-wave
    float*          redw = (float*)SCRU;           // [8] wave partials
    unsigned short* Vb4  = &Vb[0][0];              // V^T: [E(4)][g(8)][dh(16)][uk(16)]

    const int t = threadIdx.x;
    const int w = t >> 6, lane = t & 63;           // w = 0..7
    const int q = lane >> 4, ln = lane & 15;

    // ================= BN-stats path (last SBLK blocks) =================
    if (blockIdx.x >= NBLK) {
        float* NUMs = (float*)ACT;            // [16][104]
        float* cred = (float*)Qb;             // [8][128]
        float* cS   = (float*)Vb;             // [128]
        const int b0 = (blockIdx.x - NBLK) * 16;
        const int j = t & 127, sg = t >> 7, s0 = sg * 4;   // sg = 0..3, 4 rows each

        for (int idx = t; idx < 16 * NUMF_SZ; idx += 512) {
            int r = idx / NUMF_SZ, f = idx - r * NUMF_SZ;
            NUMs[r * 104 + f] = num[(size_t)(b0 + r) * NUMF_SZ + f];
        }
        __syncthreads();

        float acc[4];
        float bnv = bnum[j];
#pragma unroll
        for (int r = 0; r < 4; ++r) acc[r] = bnv;
        for (int f = 0; f < NUMF_SZ; ++f) {
            float wv = Wn[f * 128 + j];
#pragma unroll
            for (int r = 0; r < 4; ++r) acc[r] = fmaf(NUMs[(s0 + r) * 104 + f], wv, acc[r]);
        }
        float lsum = 0.f, lsq = 0.f;
#pragma unroll
        for (int r = 0; r < 4; ++r) {
            lsum += acc[r];
            lsq = fmaf(acc[r], acc[r], lsq);
        }
        cred[sg * 128 + j] = lsum;
        cred[(4 + sg) * 128 + j] = lsq;
        __syncthreads();
        if (sg == 0) atomicAdd(&ssum[j], (cred[j] + cred[128 + j]) +
                                         (cred[256 + j] + cred[384 + j]));
        else if (sg == 1) atomicAdd(&ssq[j], (cred[512 + j] + cred[640 + j]) +
                                             (cred[768 + j] + cred[896 + j]));
        __syncthreads();   // drains this block's atomics before counter bump
        if (t == 0) lastf = (atomicAdd(cnt, 1u) == SBLK - 1u) ? 1 : 0;
        __syncthreads();

        // Last block: fold BN through Wn -> cvec (103 coeffs + C1).
        if (lastf) {
            float C1p = 0.f;
            if (t < 128) {
                float sv = atomicAdd(&ssum[t], 0.f);   // device-coherent read
                float qv = atomicAdd(&ssq[t], 0.f);
                float mean = sv * (1.0f / (float)B_SZ);
                float var = qv * (1.0f / (float)B_SZ) - mean * mean;
                float inv = rsqrtf(var + 1e-5f);
                float wj = Wf[2088 + t];
                float gi = bng[t] * inv;
                float cj = gi * wj;
                cS[t] = cj;
                C1p = (bnb[t] - mean * gi) * wj + bnum[t] * cj;
            }
#pragma unroll
            for (int o = 32; o; o >>= 1) C1p += __shfl_xor(C1p, o);
            if (lane == 0) redw[w] = C1p;
            __syncthreads();
            if (t == 0) cvec[103] = ((redw[0] + redw[1]) + (redw[2] + redw[3])) +
                                    ((redw[4] + redw[5]) + (redw[6] + redw[7])) + bfin[0];
            if (t < NUMF_SZ) {
                float s2 = 0.f;
                for (int jj = 0; jj < 128; ++jj)
                    s2 = fmaf(Wn[t * 128 + jj], cS[jj], s2);
                cvec[t] = s2;
            }
        }
        return;
    }

    // ================= encoder path ======================
    const int bbase = blockIdx.x * G_B;
    const int n0 = w * 16 + q * 4;        // this wave's output column base

    // ---- load x + PE -> ACT (bf16) ----
    {
        const float4* xb = (const float4*)(x + (size_t)bbase * 2048);
        const float4* pe4 = (const float4*)PEt;
#pragma unroll
        for (int i = 0; i < 4; ++i) {
            int f4 = i * 512 + t;                  // 0..2047
            float4 xv = xb[f4];
            float4 pv = pe4[f4 & 511];
            int flat = f4 * 4;
            int row = flat >> 7, col = flat & 127;
            ushort4 pk = {f2b(xv.x + pv.x), f2b(xv.y + pv.y),
                          f2b(xv.z + pv.z), f2b(xv.w + pv.w)};
            *(ushort4*)&ACT[row][col] = pk;
        }
    }
    __syncthreads();

    for (int l = 0; l < 2; ++l) {
        // ================= QKV (wave handles n-tile w) =================
        {
            bh8 afr[4][4];
#pragma unroll
            for (int mt = 0; mt < 4; ++mt)
#pragma unroll
                for (int ks = 0; ks < 4; ++ks)
                    afr[mt][ks] = *(const bh8*)&ACT[mt * 16 + ln][ks * 32 + q * 8];
            // ---- Q and K: swapped-C, packed ushort4 stores ----
#pragma unroll
            for (int mtx = 0; mtx < 2; ++mtx) {
                const unsigned short* Wm = (mtx == 0) ? WswQ + l * 16384 : WswK + l * 16384;
                const float* bias = (mtx == 0) ? bq + l * 128 : bk + l * 128;
                unsigned short (*dst)[STRD] = (mtx == 0) ? Qb : Kb;
                bh8 wfr[4];
#pragma unroll
                for (int ks = 0; ks < 4; ++ks)
                    wfr[ks] = *(const bh8*)(Wm + ((w * 4 + ks) * 64 + lane) * 8);
                fx4 bb4 = *(const fx4*)&bias[n0];
#pragma unroll
                for (int mt = 0; mt < 4; ++mt) {
                    fx4 acc = {0.f, 0.f, 0.f, 0.f};
#pragma unroll
                    for (int ks = 0; ks < 4; ++ks) acc = mfma16(wfr[ks], afr[mt][ks], acc);
                    us4 o;
#pragma unroll
                    for (int r2 = 0; r2 < 4; ++r2) o[r2] = f2b(acc[r2] + bb4[r2]);
                    *(us4*)&dst[mt * 16 + ln][n0] = o;
                }
            }
            // ---- V: normal-C orientation, scattered into V^T layout ----
            {
                bh8 wfr[4];
#pragma unroll
                for (int ks = 0; ks < 4; ++ks)
                    wfr[ks] = *(const bh8*)(WswV + l * 16384 + ((w * 4 + ks) * 64 + lane) * 8);
                int n = w * 16 + ln;
                float bb = bv[l * 128 + n];
#pragma unroll
                for (int mt = 0; mt < 4; ++mt) {
                    fx4 acc = {0.f, 0.f, 0.f, 0.f};
#pragma unroll
                    for (int ks = 0; ks < 4; ++ks) acc = mfma16(afr[mt][ks], wfr[ks], acc);
                    // Vt[E][g][dh][uk]: E=mt, s=q*4+r2, g=s>>1, dh=ln,
                    // uk=((s&1)<<3)|w
#pragma unroll
                    for (int r2 = 0; r2 < 4; ++r2) {
                        int s = q * 4 + r2;
                        Vb4[(((mt * 8 + (s >> 1)) * 16) + ln) * 16 +
                            (((s & 1) << 3) | w)] = f2b(acc[r2] + bb);
                    }
                }
            }
        }
        __syncthreads();

        // ===== attention: 2 waves per element, 4 heads per wave =====
        {
            const int e = w >> 1;
            const int g4 = (w & 1) * 4;
            const int rbase = e * 16 + (ln >> 3);   // + 2g per head
            const int ccol = (ln & 7) * 16;
#pragma unroll
            for (int g2 = 0; g2 < 4; ++g2) {
                int g = g4 + g2;
                bh8 kfr = 0, qfr = 0;
                if (q < 2) {
                    kfr = *(const bh8*)&Kb[rbase + 2 * g][ccol + q * 8];
                    qfr = *(const bh8*)&Qb[rbase + 2 * g][ccol + q * 8];
                }
                fx4 st = mfma16(kfr, qfr, fx4{0.f, 0.f, 0.f, 0.f});
                float p0 = st[0] * 0.25f, p1 = st[1] * 0.25f;
                float p2 = st[2] * 0.25f, p3 = st[3] * 0.25f;
                float mx = fmaxf(fmaxf(p0, p1), fmaxf(p2, p3));
                mx = fmaxf(mx, __shfl_xor(mx, 16));
                mx = fmaxf(mx, __shfl_xor(mx, 32));
                p0 = __expf(p0 - mx); p1 = __expf(p1 - mx);
                p2 = __expf(p2 - mx); p3 = __expf(p3 - mx);
                float sm = (p0 + p1) + (p2 + p3);
                sm += __shfl_xor(sm, 16);
                sm += __shfl_xor(sm, 32);
                float is = 1.0f / sm;
                ushort4 pk = {f2b(p0 * is), f2b(p1 * is), f2b(p2 * is), f2b(p3 * is)};
                *(ushort4*)&Pb[(w * 16 + ln) * 16 + q * 4] = pk;
                bh8 vfr = 0, pfr = 0;
                if (q < 2) {
                    vfr = *(const bh8*)&Vb4[(((e * 8 + g) * 16) + ln) * 16 + q * 8];
                    pfr = *(const bh8*)&Pb[(w * 16 + ln) * 16 + q * 8];
                }
                fx4 cx = mfma16(vfr, pfr, fx4{0.f, 0.f, 0.f, 0.f});
                ushort4 ck = {f2b(cx[0]), f2b(cx[1]), f2b(cx[2]), f2b(cx[3])};
                *(ushort4*)&Qb[rbase + 2 * g][ccol + q * 4] = ck;
            }
        }
        __syncthreads();

        // ========= O-proj (swapped-C) + residual + LN1 -> Kb (H) ===========
        fx4 Cv[4];
        {
            bh8 cfr[4][4];
#pragma unroll
            for (int mt = 0; mt < 4; ++mt)
#pragma unroll
                for (int ks = 0; ks < 4; ++ks)
                    cfr[mt][ks] = *(const bh8*)&Qb[mt * 16 + ln][ks * 32 + q * 8];
            bh8 wfr[4];
#pragma unroll
            for (int ks = 0; ks < 4; ++ks)
                wfr[ks] = *(const bh8*)(WswO + l * 16384 + ((w * 4 + ks) * 64 + lane) * 8);
            fx4 bb4 = *(const fx4*)&bo[l * 128 + n0];
#pragma unroll
            for (int mt = 0; mt < 4; ++mt) {
                fx4 acc = {0.f, 0.f, 0.f, 0.f};
#pragma unroll
                for (int ks = 0; ks < 4; ++ks) acc = mfma16(wfr[ks], cfr[mt][ks], acc);
                us4 rv = *(const us4*)&ACT[mt * 16 + ln][n0];
#pragma unroll
                for (int r2 = 0; r2 < 4; ++r2)
                    Cv[mt][r2] = acc[r2] + bb4[r2] + bu2f(rv[r2]);
            }
        }
        // LN1: per-wave partial over its 16 cols (2 shuffles), one barrier
#pragma unroll
        for (int mt = 0; mt < 4; ++mt) {
            float s = 0.f, v = 0.f;
#pragma unroll
            for (int r2 = 0; r2 < 4; ++r2) {
                float a = Cv[mt][r2];
                s += a; v = fmaf(a, a, v);
            }
            s += __shfl_xor(s, 16); v += __shfl_xor(v, 16);
            s += __shfl_xor(s, 32); v += __shfl_xor(v, 32);
            if (lane < 16) LNp2[(mt * 16 + ln) * 8 + w] = float2{s, v};
        }
        __syncthreads();
        {
            float mean4[4], inv4[4];
#pragma unroll
            for (int mt = 0; mt < 4; ++mt) {
                int row = mt * 16 + ln;
                float s = 0.f, v = 0.f;
#pragma unroll
                for (int ww = 0; ww < 8; ++ww) {
                    float2 a = LNp2[row * 8 + ww];
                    s += a.x; v += a.y;
                }
                float mean = s * (1.0f / 128.0f);
                mean4[mt] = mean;
                inv4[mt] = rsqrtf(v * (1.0f / 128.0f) - mean * mean + 1e-5f);
            }
            fx4 gg = *(const fx4*)&ln1g[l * 128 + n0];
            fx4 be = *(const fx4*)&ln1b[l * 128 + n0];
#pragma unroll
            for (int mt = 0; mt < 4; ++mt) {
                us4 o;
#pragma unroll
                for (int r2 = 0; r2 < 4; ++r2)
                    o[r2] = f2b((Cv[mt][r2] - mean4[mt]) * inv4[mt] * gg[r2] + be[r2]);
                *(us4*)&Kb[mt * 16 + ln][n0] = o;
            }
        }
        __syncthreads();

        // ================= FF (8 chunks of 128 hidden) ======================
        // hfr reloaded per chunk (keeps FF live-set under the 128-VGPR cap).
        fx4 f2a[4];
#pragma unroll
        for (int mt = 0; mt < 4; ++mt) f2a[mt] = fx4{0.f, 0.f, 0.f, 0.f};
        for (int ch = 0; ch < 8; ++ch) {
            unsigned short (*dst)[STRD] = (ch & 1) ? Vb : Qb;
            bh8 w1fr[4];
            int ntg = ch * 8 + w;
#pragma unroll
            for (int ks = 0; ks < 4; ++ks)
                w1fr[ks] = *(const bh8*)(Wsw1 + l * 131072 + ((ntg * 4 + ks) * 64 + lane) * 8);
            fx4 bb4 = *(const fx4*)&b1[l * HID_SZ + ch * 128 + n0];
#pragma unroll
            for (int mt = 0; mt < 4; ++mt) {
                bh8 hfr[4];
#pragma unroll
                for (int ks = 0; ks < 4; ++ks)
                    hfr[ks] = *(const bh8*)&Kb[mt * 16 + ln][ks * 32 + q * 8];
                fx4 acc = {0.f, 0.f, 0.f, 0.f};
#pragma unroll
                for (int ks = 0; ks < 4; ++ks) acc = mfma16(w1fr[ks], hfr[ks], acc);
                us4 o;
#pragma unroll
                for (int r2 = 0; r2 < 4; ++r2) {
                    float vv = acc[r2] + bb4[r2];
                    o[r2] = f2b(vv > 0.f ? vv : 0.f);
                }
                *(us4*)&dst[mt * 16 + ln][n0] = o;
            }
            __syncthreads();
            bh8 w2fr[4];
#pragma unroll
            for (int ks = 0; ks < 4; ++ks)
                w2fr[ks] = *(const bh8*)(Wsw2 + l * 131072 +
                    ((w * 32 + ch * 4 + ks) * 64 + lane) * 8);
#pragma unroll
            for (int mt = 0; mt < 4; ++mt) {
                bh8 ffr[4];
#pragma unroll
                for (int ks = 0; ks < 4; ++ks)
                    ffr[ks] = *(const bh8*)&dst[mt * 16 + ln][ks * 32 + q * 8];
#pragma unroll
                for (int ks = 0; ks < 4; ++ks)
                    f2a[mt] = mfma16(w2fr[ks], ffr[ks], f2a[mt]);
            }
            // no trailing barrier: ping-pong buffered (WAR covered by next
            // chunk's barrier; waitcnts drain before s_barrier)
        }
        // epilogue: + b2 + H residual, LN2 -> ACT (same inline-LN scheme)
        fx4 Cv2[4];
        {
            fx4 bb4 = *(const fx4*)&b2p[l * 128 + n0];
#pragma unroll
            for (int mt = 0; mt < 4; ++mt) {
                us4 rv = *(const us4*)&Kb[mt * 16 + ln][n0];
#pragma unroll
                for (int r2 = 0; r2 < 4; ++r2)
                    Cv2[mt][r2] = f2a[mt][r2] + bb4[r2] + bu2f(rv[r2]);
            }
        }
#pragma unroll
        for (int mt = 0; mt < 4; ++mt) {
            float s = 0.f, v = 0.f;
#pragma unroll
            for (int r2 = 0; r2 < 4; ++r2) {
                float a = Cv2[mt][r2];
                s += a; v = fmaf(a, a, v);
            }
            s += __shfl_xor(s, 16); v += __shfl_xor(v, 16);
            s += __shfl_xor(s, 32); v += __shfl_xor(v, 32);
            if (lane < 16) LNp2[(mt * 16 + ln) * 8 + w] = float2{s, v};
        }
        __syncthreads();
        {
            float mean4[4], inv4[4];
#pragma unroll
            for (int mt = 0; mt < 4; ++mt) {
                int row = mt * 16 + ln;
                float s = 0.f, v = 0.f;
#pragma unroll
                for (int ww = 0; ww < 8; ++ww) {
                    float2 a = LNp2[row * 8 + ww];
                    s += a.x; v += a.y;
                }
                float mean = s * (1.0f / 128.0f);
                mean4[mt] = mean;
                inv4[mt] = rsqrtf(v * (1.0f / 128.0f) - mean * mean + 1e-5f);
            }
            fx4 gg = *(const fx4*)&ln2g[l * 128 + n0];
            fx4 be = *(const fx4*)&ln2b[l * 128 + n0];
#pragma unroll
            for (int mt = 0; mt < 4; ++mt) {
                us4 o;
#pragma unroll
                for (int r2 = 0; r2 < 4; ++r2)
                    o[r2] = f2b((Cv2[mt][r2] - mean4[mt]) * inv4[mt] * gg[r2] + be[r2]);
                *(us4*)&ACT[mt * 16 + ln][n0] = o;
            }
        }
        __syncthreads();
    }

    // ====== head partial dot: 2 waves per batch element (e = w>>1) =========
    {
        const int e = w >> 1, h2 = w & 1;
        int bg = bbase + e;
        float part = 0.f;
        int r = h2 * 8 + (lane >> 3), c0 = (lane & 7) * 16;
#pragma unroll
        for (int i = 0; i < 2; ++i) {
            bh8 av = *(const bh8*)&ACT[e * 16 + r][c0 + i * 8];
            int fl = r * 128 + c0 + i * 8;
#pragma unroll
            for (int e8 = 0; e8 < 8; ++e8)
                part = fmaf(bu2f((unsigned short)av[e8]), Wf[fl + e8], part);
        }
        if (lane < 20) {
            int gi = h2 * 20 + lane;
            part = fmaf(gcn[(size_t)bg * GCN_SZ + gi], Wf[2048 + gi], part);
        }
#pragma unroll
        for (int off = 32; off; off >>= 1) part += __shfl_xor(part, off);
        if (lane == 0) redw[w] = part;
    }
    __syncthreads();
    if (t < G_B)
        acc1[bbase + t] = redw[2 * t] + redw[2 * t + 1];
}

// One wave per batch row: dot(num[b], wnc) + acc1[b] + C1 -> sigmoid.
__global__ __launch_bounds__(256) void final_fast(
    const float* __restrict__ num, const float* __restrict__ cvec,
    const float* __restrict__ acc1, float* __restrict__ out)
{
    __shared__ float wv[104];
    const int t = threadIdx.x;
    if (t < 104) wv[t] = cvec[t];
    __syncthreads();
    const int w = t >> 6, lane = t & 63;
    const int b = blockIdx.x * 4 + w;
    const float* nb = num + (size_t)b * NUMF_SZ;
    float part = nb[lane] * wv[lane];
    if (lane < NUMF_SZ - 64) part += nb[64 + lane] * wv[64 + lane];
#pragma unroll
    for (int o = 32; o; o >>= 1) part += __shfl_xor(part, o);
    if (lane == 0)
        out[b] = 1.0f / (1.0f + __expf(-(acc1[b] + part + wv[103])));
}

extern "C" void kernel_launch(void* const* d_in, const int* in_sizes, int n_in,
                              void* d_out, int out_size, void* d_ws, size_t ws_size,
                              hipStream_t stream)
{
    const float* x    = (const float*)d_in[0];
    const float* gcn  = (const float*)d_in[1];
    const float* num  = (const float*)d_in[2];
    const float* Wq   = (const float*)d_in[3];
    const float* bq   = (const float*)d_in[4];
    const float* Wk   = (const float*)d_in[5];
    const float* bk   = (const float*)d_in[6];
    const float* Wv   = (const float*)d_in[7];
    const float* bv   = (const float*)d_in[8];
    const float* Wo   = (const float*)d_in[9];
    const float* bo   = (const float*)d_in[10];
    const float* ln1g = (const float*)d_in[11];
    const float* ln1b = (const float*)d_in[12];
    const float* W1   = (const float*)d_in[13];
    const float* b1   = (const float*)d_in[14];
    const float* W2   = (const float*)d_in[15];
    const float* b2p  = (const float*)d_in[16];
    const float* ln2g = (const float*)d_in[17];
    const float* ln2b = (const float*)d_in[18];
    const float* Wn   = (const float*)d_in[19];
    const float* bnum = (const float*)d_in[20];
    const float* bng  = (const float*)d_in[21];
    const float* bnb  = (const float*)d_in[22];
    const float* Wf   = (const float*)d_in[23];
    const float* bfin = (const float*)d_in[24];

    // ws: acc1 (8192 f32) | ssum(128) | ssq(128) | cnt(1) | pad to 40960
    //     | swizzled bf16 weights | PE (8 KB) | cvec (104 f32)
    float* acc1 = (float*)d_ws;
    float* ssum = acc1 + B_SZ;
    float* ssq  = ssum + 128;
    unsigned int* cnt = (unsigned int*)(ssq + 128);
    unsigned short* wb = (unsigned short*)((char*)d_ws + 40960);
    unsigned short* WswQ = wb;
    unsigned short* WswK = wb + 32768;
    unsigned short* WswV = wb + 65536;
    unsigned short* WswO = wb + 98304;
    unsigned short* Wsw1 = wb + 131072;
    unsigned short* Wsw2 = wb + 393216;
    float* PEt = (float*)((char*)d_ws + 40960 + 1310720);
    float* cvec = (float*)((char*)d_ws + 40960 + 1310720 + 8192);

    hipMemsetAsync(ssum, 0, 257 * sizeof(float), stream);
    prep_weights<<<1024, 256, 0, stream>>>(Wq, Wk, Wv, Wo, W1, W2,
        WswQ, WswK, WswV, WswO, Wsw1, Wsw2, PEt);
    encoder_fused<<<NBLK + SBLK, 512, 0, stream>>>(x, gcn, bq, bk, bv, bo,
        ln1g, ln1b, b1, b2p, ln2g, ln2b, Wf,
        WswQ, WswK, WswV, WswO, Wsw1, Wsw2, PEt,
        num, Wn, bnum, ssum, ssq, cnt, bng, bnb, bfin, cvec, acc1);
    final_fast<<<B_SZ / 4, 256, 0, stream>>>(num, cvec, acc1, (float*)d_out);
}

// Round 10
// 393.852 us; speedup vs baseline: 1.1171x; 1.1171x over previous
//
#include <hip/hip_runtime.h>
#include <hip/hip_bf16.h>
#include <math.h>

#define B_SZ   8192
#define S_SZ   16
#define D_SZ   128
#define HID_SZ 1024
#define NUMF_SZ 103
#define GCN_SZ 40
#define G_B    4                 // batch elements per block (64 rows)
#define NBLK   (B_SZ / G_B)      // 2048 encoder blocks
#define SBLK   512               // stats blocks appended AFTER encoder blocks
#define STRD   136               // LDS row stride (shorts), pad 8

typedef short bh8 __attribute__((ext_vector_type(8)));   // 8 bf16 (4 VGPRs)
typedef float fx4 __attribute__((ext_vector_type(4)));   // MFMA accumulator
typedef unsigned short us4 __attribute__((ext_vector_type(4))); // 4 bf16 (8B)

__device__ __forceinline__ fx4 mfma16(bh8 a, bh8 b, fx4 c) {
    return __builtin_amdgcn_mfma_f32_16x16x32_bf16(a, b, c, 0, 0, 0);
}

// fp32 -> bf16 bits via native conversion (RNE, 1 VALU op)
__device__ __forceinline__ unsigned short f2b(float f) {
    union { __hip_bfloat16 b; unsigned short u; } cv;
    cv.b = __float2bfloat16(f);
    return cv.u;
}
__device__ __forceinline__ float bu2f(unsigned short u) {
    return __uint_as_float(((unsigned)u) << 16);
}

// Weight swizzle (src-driven, coalesced reads, scatter 2B writes):
//   QKVO : [l][nt(8)][ks(4)][lane(64)][e(8)]
//   W1   : [l][nt(64)][ks(4)][lane][e]
//   W2   : [l][nt(8)][kt(32)][lane][e]
__global__ __launch_bounds__(256) void prep_weights(
    const float* __restrict__ Wq, const float* __restrict__ Wk,
    const float* __restrict__ Wv, const float* __restrict__ Wo,
    const float* __restrict__ W1, const float* __restrict__ W2,
    unsigned short* __restrict__ WswQ, unsigned short* __restrict__ WswK,
    unsigned short* __restrict__ WswV, unsigned short* __restrict__ WswO,
    unsigned short* __restrict__ Wsw1, unsigned short* __restrict__ Wsw2,
    float* __restrict__ PEt)
{
    int j = blockIdx.x * 256 + threadIdx.x;   // 0..262143
    if (j < 2048) {  // PE table [16][128]
        int s = j >> 7, c = j & 127;
        float expo = (float)((c >> 1) * 2) * (1.0f / 128.0f);
        float denom = powf(10000.0f, expo);
        float ang = (float)s / denom;
        PEt[j] = (c & 1) ? cosf(ang) : sinf(ang);
    }
    if (j < 2 * 16384) {   // QKVO: src [l][k=128][n=128]
        int r = j & 16383, l = j >> 14;
        int k = r >> 7, n = r & 127;
        int dst = (((l * 8 + (n >> 4)) * 4 + (k >> 5)) * 64 +
                   (((k >> 3) & 3) * 16 + (n & 15))) * 8 + (k & 7);
        WswQ[dst] = f2b(Wq[j]); WswK[dst] = f2b(Wk[j]);
        WswV[dst] = f2b(Wv[j]); WswO[dst] = f2b(Wo[j]);
    }
    {   // W1: src [l][k=128][n=1024]
        int l = j >> 17, r = j & 131071;
        int k = r >> 10, n = r & 1023;
        int dst = (((l * 64 + (n >> 4)) * 4 + (k >> 5)) * 64 +
                   (((k >> 3) & 3) * 16 + (n & 15))) * 8 + (k & 7);
        Wsw1[dst] = f2b(W1[j]);
    }
    {   // W2: src [l][k=1024][n=128]
        int l = j >> 17, r = j & 131071;
        int k = r >> 7, n = r & 127;
        int dst = (((l * 8 + (n >> 4)) * 32 + (k >> 5)) * 64 +
                   (((k >> 3) & 3) * 16 + (n & 15))) * 8 + (k & 7);
        Wsw2[dst] = f2b(W2[j]);
    }
}

// Mega kernel (256-thread blocks, R7 encoder structure):
//   blocks [0, NBLK)         = encoder path
//   blocks [NBLK, NBLK+SBLK) = BN-stats path (+ last-block cvec)
// Stats blocks APPENDED so they backfill the encoder's drain tail (R8 had
// them first, which delayed every encoder block by one stats-round: +28us).
__global__ __launch_bounds__(256, 2) void encoder_fused(
    const float* __restrict__ x, const float* __restrict__ gcn,
    const float* __restrict__ bq, const float* __restrict__ bk,
    const float* __restrict__ bv, const float* __restrict__ bo,
    const float* __restrict__ ln1g, const float* __restrict__ ln1b,
    const float* __restrict__ b1, const float* __restrict__ b2p,
    const float* __restrict__ ln2g, const float* __restrict__ ln2b,
    const float* __restrict__ Wf,
    const unsigned short* __restrict__ WswQ, const unsigned short* __restrict__ WswK,
    const unsigned short* __restrict__ WswV, const unsigned short* __restrict__ WswO,
    const unsigned short* __restrict__ Wsw1, const unsigned short* __restrict__ Wsw2,
    const float* __restrict__ PEt,
    const float* __restrict__ num, const float* __restrict__ Wn,
    const float* __restrict__ bnum,
    float* __restrict__ ssum, float* __restrict__ ssq,
    unsigned int* __restrict__ cnt,
    const float* __restrict__ bng, const float* __restrict__ bnb,
    const float* __restrict__ bfin, float* __restrict__ cvec,
    float* __restrict__ acc1)
{
    __shared__ unsigned short ACT[64][STRD];  // activations / LN2 output
    __shared__ unsigned short Qb[64][STRD];   // Q -> ctx -> FF1 chunk (even)
    __shared__ unsigned short Kb[64][STRD];   // K -> H (post-LN1)
    __shared__ unsigned short Vb[64][STRD];   // V^T (per-head) -> FF1 chunk (odd)
    __shared__ float2 LNp2[64][4];            // per-row per-wave (sum, sumsq)
    __shared__ unsigned short Pb[4][16][16];  // per-wave P tile (softmax probs)
    __shared__ int lastf;

    unsigned short* Vb4 = &Vb[0][0];          // V^T alias: [E(4)][g(8)][dh(16)][uk(16)]

    const int t = threadIdx.x;
    const int w = t >> 6, lane = t & 63;
    const int q = lane >> 4, ln = lane & 15;

    // ================= BN-stats path (last SBLK blocks) =================
    if (blockIdx.x >= NBLK) {
        float* NUMs = (float*)ACT;            // [16][104]
        float* cred = (float*)Qb;             // [4][128]
        float* cS   = (float*)Vb;             // [128]
        float* redw = (float*)LNp2;           // [4]
        const int b0 = (blockIdx.x - NBLK) * 16;
        const int j = t & 127, sg = t >> 7, s0 = sg * 8;

        for (int idx = t; idx < 16 * NUMF_SZ; idx += 256) {
            int r = idx / NUMF_SZ, f = idx - r * NUMF_SZ;
            NUMs[r * 104 + f] = num[(size_t)(b0 + r) * NUMF_SZ + f];
        }
        __syncthreads();

        float acc[8];
        float bnv = bnum[j];
#pragma unroll
        for (int r = 0; r < 8; ++r) acc[r] = bnv;
        for (int f = 0; f < NUMF_SZ; ++f) {
            float wv = Wn[f * 128 + j];
#pragma unroll
            for (int r = 0; r < 8; ++r) acc[r] = fmaf(NUMs[(s0 + r) * 104 + f], wv, acc[r]);
        }
        float lsum = 0.f, lsq = 0.f;
#pragma unroll
        for (int r = 0; r < 8; ++r) {
            lsum += acc[r];
            lsq = fmaf(acc[r], acc[r], lsq);
        }
        cred[sg * 128 + j] = lsum;
        cred[(2 + sg) * 128 + j] = lsq;
        __syncthreads();
        if (sg == 0) atomicAdd(&ssum[j], cred[j] + cred[128 + j]);
        else         atomicAdd(&ssq[j],  cred[256 + j] + cred[384 + j]);
        __syncthreads();   // drains this block's atomics before counter bump
        if (t == 0) lastf = (atomicAdd(cnt, 1u) == SBLK - 1u) ? 1 : 0;
        __syncthreads();

        // Last block: fold BN through Wn -> cvec (103 coeffs + C1).
        //   c_j = inv_j*gamma_j*Wf3_j; wnc_f = sum_j Wn[f][j]*c_j;
        //   C1 = sum_j ((beta_j - mean_j*inv_j*gamma_j)*Wf3_j + bnum_j*c_j) + bf
        if (lastf) {
            float C1p = 0.f;
            if (t < 128) {
                float sv = atomicAdd(&ssum[t], 0.f);   // device-coherent read
                float qv = atomicAdd(&ssq[t], 0.f);
                float mean = sv * (1.0f / (float)B_SZ);
                float var = qv * (1.0f / (float)B_SZ) - mean * mean;
                float inv = rsqrtf(var + 1e-5f);
                float wj = Wf[2088 + t];
                float gi = bng[t] * inv;
                float cj = gi * wj;
                cS[t] = cj;
                C1p = (bnb[t] - mean * gi) * wj + bnum[t] * cj;
            }
#pragma unroll
            for (int o = 32; o; o >>= 1) C1p += __shfl_xor(C1p, o);
            if (lane == 0) redw[w] = C1p;
            __syncthreads();
            if (t == 0) cvec[103] = redw[0] + redw[1] + redw[2] + redw[3] + bfin[0];
            if (t < NUMF_SZ) {
                float s2 = 0.f;
                for (int jj = 0; jj < 128; ++jj)
                    s2 = fmaf(Wn[t * 128 + jj], cS[jj], s2);
                cvec[t] = s2;
            }
        }
        return;
    }

    // ================= encoder path (R7 structure) ======================
    const int bbase = blockIdx.x * G_B;

    // ---- load x + PE -> ACT (bf16) ----
    {
        const float4* xb = (const float4*)(x + (size_t)bbase * 2048);
        const float4* pe4 = (const float4*)PEt;
#pragma unroll
        for (int i = 0; i < 8; ++i) {
            int f4 = i * 256 + t;                  // 0..2047
            float4 xv = xb[f4];
            float4 pv = pe4[f4 & 511];
            int flat = f4 * 4;
            int row = flat >> 7, col = flat & 127;
            ushort4 pk = {f2b(xv.x + pv.x), f2b(xv.y + pv.y),
                          f2b(xv.z + pv.z), f2b(xv.w + pv.w)};
            *(ushort4*)&ACT[row][col] = pk;
        }
    }
    __syncthreads();

    for (int l = 0; l < 2; ++l) {
        // ================= QKV =================
        {
            bh8 afr[4][4];
#pragma unroll
            for (int mt = 0; mt < 4; ++mt)
#pragma unroll
                for (int ks = 0; ks < 4; ++ks)
                    afr[mt][ks] = *(const bh8*)&ACT[mt * 16 + ln][ks * 32 + q * 8];
            // ---- Q and K: swapped-C, packed ushort4 stores ----
#pragma unroll
            for (int mtx = 0; mtx < 2; ++mtx) {
                const unsigned short* Wm = (mtx == 0) ? WswQ + l * 16384 : WswK + l * 16384;
                const float* bias = (mtx == 0) ? bq + l * 128 : bk + l * 128;
                unsigned short (*dst)[STRD] = (mtx == 0) ? Qb : Kb;
#pragma unroll
                for (int i2 = 0; i2 < 2; ++i2) {
                    int nt = w * 2 + i2;
                    bh8 wfr[4];
#pragma unroll
                    for (int ks = 0; ks < 4; ++ks)
                        wfr[ks] = *(const bh8*)(Wm + ((nt * 4 + ks) * 64 + lane) * 8);
                    int n0 = nt * 16 + q * 4;
                    fx4 bb4 = *(const fx4*)&bias[n0];
#pragma unroll
                    for (int mt = 0; mt < 4; ++mt) {
                        fx4 acc = {0.f, 0.f, 0.f, 0.f};
#pragma unroll
                        for (int ks = 0; ks < 4; ++ks) acc = mfma16(wfr[ks], afr[mt][ks], acc);
                        us4 o;
#pragma unroll
                        for (int r2 = 0; r2 < 4; ++r2) o[r2] = f2b(acc[r2] + bb4[r2]);
                        *(us4*)&dst[mt * 16 + ln][n0] = o;
                    }
                }
            }
            // ---- V: normal-C orientation, scattered into V^T layout ----
#pragma unroll
            for (int i2 = 0; i2 < 2; ++i2) {
                int nt = w * 2 + i2;
                bh8 wfr[4];
#pragma unroll
                for (int ks = 0; ks < 4; ++ks)
                    wfr[ks] = *(const bh8*)(WswV + l * 16384 + ((nt * 4 + ks) * 64 + lane) * 8);
                int n = nt * 16 + ln;
                float bb = bv[l * 128 + n];
#pragma unroll
                for (int mt = 0; mt < 4; ++mt) {
                    fx4 acc = {0.f, 0.f, 0.f, 0.f};
#pragma unroll
                    for (int ks = 0; ks < 4; ++ks) acc = mfma16(afr[mt][ks], wfr[ks], acc);
                    // Vt[E][g][dh][uk]: (s,d) -> g=s>>1, uk=((s&1)<<3)|nt, dh=ln
#pragma unroll
                    for (int r2 = 0; r2 < 4; ++r2) {
                        int s = q * 4 + r2;
                        Vb4[(((mt * 8 + (s >> 1)) * 16) + ln) * 16 +
                            (((s & 1) << 3) | nt)] = f2b(acc[r2] + bb);
                    }
                }
            }
        }
        __syncthreads();

        // ===== attention, MFMA-based, wave-local: wave w owns element w =====
        {
            const int E = w;
            const int rbase = E * 16 + (ln >> 3);   // + 2g per head
            const int ccol = (ln & 7) * 16;
#pragma unroll
            for (int g = 0; g < 8; ++g) {
                bh8 kfr = 0, qfr = 0;
                if (q < 2) {
                    kfr = *(const bh8*)&Kb[rbase + 2 * g][ccol + q * 8];
                    qfr = *(const bh8*)&Qb[rbase + 2 * g][ccol + q * 8];
                }
                fx4 st = mfma16(kfr, qfr, fx4{0.f, 0.f, 0.f, 0.f});
                float p0 = st[0] * 0.25f, p1 = st[1] * 0.25f;
                float p2 = st[2] * 0.25f, p3 = st[3] * 0.25f;
                float mx = fmaxf(fmaxf(p0, p1), fmaxf(p2, p3));
                mx = fmaxf(mx, __shfl_xor(mx, 16));
                mx = fmaxf(mx, __shfl_xor(mx, 32));
                p0 = __expf(p0 - mx); p1 = __expf(p1 - mx);
                p2 = __expf(p2 - mx); p3 = __expf(p3 - mx);
                float sm = (p0 + p1) + (p2 + p3);
                sm += __shfl_xor(sm, 16);
                sm += __shfl_xor(sm, 32);
                float is = 1.0f / sm;
                ushort4 pk = {f2b(p0 * is), f2b(p1 * is), f2b(p2 * is), f2b(p3 * is)};
                *(ushort4*)&Pb[w][ln][q * 4] = pk;   // Pb[u_q][u_k]=P[u_q][u_k]
                bh8 vfr = 0, pfr = 0;
                if (q < 2) {
                    vfr = *(const bh8*)&Vb4[(((E * 8 + g) * 16) + ln) * 16 + q * 8];
                    pfr = *(const bh8*)&Pb[w][ln][q * 8];
                }
                fx4 cx = mfma16(vfr, pfr, fx4{0.f, 0.f, 0.f, 0.f});
                ushort4 ck = {f2b(cx[0]), f2b(cx[1]), f2b(cx[2]), f2b(cx[3])};
                *(ushort4*)&Qb[rbase + 2 * g][ccol + q * 4] = ck;
            }
        }
        __syncthreads();

        // ========= O-proj (swapped-C) + residual + LN1 -> Kb (H) ===========
        fx4 Cv[2][4];
        {
            bh8 cfr[4][4];
#pragma unroll
            for (int mt = 0; mt < 4; ++mt)
#pragma unroll
                for (int ks = 0; ks < 4; ++ks)
                    cfr[mt][ks] = *(const bh8*)&Qb[mt * 16 + ln][ks * 32 + q * 8];
#pragma unroll
            for (int i2 = 0; i2 < 2; ++i2) {
                int nt = w * 2 + i2, n0 = nt * 16 + q * 4;
                bh8 wfr[4];
#pragma unroll
                for (int ks = 0; ks < 4; ++ks)
                    wfr[ks] = *(const bh8*)(WswO + l * 16384 + ((nt * 4 + ks) * 64 + lane) * 8);
                fx4 bb4 = *(const fx4*)&bo[l * 128 + n0];
#pragma unroll
                for (int mt = 0; mt < 4; ++mt) {
                    fx4 acc = {0.f, 0.f, 0.f, 0.f};
#pragma unroll
                    for (int ks = 0; ks < 4; ++ks) acc = mfma16(wfr[ks], cfr[mt][ks], acc);
                    us4 rv = *(const us4*)&ACT[mt * 16 + ln][n0];
#pragma unroll
                    for (int r2 = 0; r2 < 4; ++r2)
                        Cv[i2][mt][r2] = acc[r2] + bb4[r2] + bu2f(rv[r2]);
                }
            }
        }
        // LN1: partials (2 shuffles), ONE barrier, inline mean/inv per thread
#pragma unroll
        for (int mt = 0; mt < 4; ++mt) {
            float s = 0.f, v = 0.f;
#pragma unroll
            for (int i2 = 0; i2 < 2; ++i2)
#pragma unroll
                for (int r2 = 0; r2 < 4; ++r2) {
                    float a = Cv[i2][mt][r2];
                    s += a; v = fmaf(a, a, v);
                }
            s += __shfl_xor(s, 16); v += __shfl_xor(v, 16);
            s += __shfl_xor(s, 32); v += __shfl_xor(v, 32);
            if (lane < 16) LNp2[mt * 16 + ln][w] = float2{s, v};
        }
        __syncthreads();
        {
            float mean4[4], inv4[4];
#pragma unroll
            for (int mt = 0; mt < 4; ++mt) {
                int row = mt * 16 + ln;
                float2 a0 = LNp2[row][0], a1 = LNp2[row][1];
                float2 a2 = LNp2[row][2], a3 = LNp2[row][3];
                float s = (a0.x + a1.x) + (a2.x + a3.x);
                float v = (a0.y + a1.y) + (a2.y + a3.y);
                float mean = s * (1.0f / 128.0f);
                mean4[mt] = mean;
                inv4[mt] = rsqrtf(v * (1.0f / 128.0f) - mean * mean + 1e-5f);
            }
#pragma unroll
            for (int i2 = 0; i2 < 2; ++i2) {
                int n0 = (w * 2 + i2) * 16 + q * 4;
                fx4 gg = *(const fx4*)&ln1g[l * 128 + n0];
                fx4 be = *(const fx4*)&ln1b[l * 128 + n0];
#pragma unroll
                for (int mt = 0; mt < 4; ++mt) {
                    us4 o;
#pragma unroll
                    for (int r2 = 0; r2 < 4; ++r2)
                        o[r2] = f2b((Cv[i2][mt][r2] - mean4[mt]) * inv4[mt] * gg[r2] + be[r2]);
                    *(us4*)&Kb[mt * 16 + ln][n0] = o;
                }
            }
        }
        __syncthreads();

        // ================= FF (8 chunks of 128 hidden) ======================
        bh8 hfr[4][4];
#pragma unroll
        for (int mt = 0; mt < 4; ++mt)
#pragma unroll
            for (int ks = 0; ks < 4; ++ks)
                hfr[mt][ks] = *(const bh8*)&Kb[mt * 16 + ln][ks * 32 + q * 8];
        fx4 f2a[2][4];
#pragma unroll
        for (int i2 = 0; i2 < 2; ++i2)
#pragma unroll
            for (int mt = 0; mt < 4; ++mt) f2a[i2][mt] = fx4{0.f, 0.f, 0.f, 0.f};
        for (int ch = 0; ch < 8; ++ch) {
            unsigned short (*dst)[STRD] = (ch & 1) ? Vb : Qb;
            bh8 w1fr[2][4];
#pragma unroll
            for (int i2 = 0; i2 < 2; ++i2) {
                int ntg = ch * 8 + w * 2 + i2;
#pragma unroll
                for (int ks = 0; ks < 4; ++ks)
                    w1fr[i2][ks] = *(const bh8*)(Wsw1 + l * 131072 + ((ntg * 4 + ks) * 64 + lane) * 8);
            }
#pragma unroll
            for (int mt = 0; mt < 4; ++mt) {
#pragma unroll
                for (int i2 = 0; i2 < 2; ++i2) {
                    fx4 acc = {0.f, 0.f, 0.f, 0.f};
#pragma unroll
                    for (int ks = 0; ks < 4; ++ks) acc = mfma16(w1fr[i2][ks], hfr[mt][ks], acc);
                    int nl0 = (w * 2 + i2) * 16 + q * 4;
                    fx4 bb4 = *(const fx4*)&b1[l * HID_SZ + ch * 128 + nl0];
                    us4 o;
#pragma unroll
                    for (int r2 = 0; r2 < 4; ++r2) {
                        float vv = acc[r2] + bb4[r2];
                        o[r2] = f2b(vv > 0.f ? vv : 0.f);
                    }
                    *(us4*)&dst[mt * 16 + ln][nl0] = o;
                }
            }
            __syncthreads();
            bh8 w2fr[2][4];
#pragma unroll
            for (int i2 = 0; i2 < 2; ++i2)
#pragma unroll
                for (int ks = 0; ks < 4; ++ks)
                    w2fr[i2][ks] = *(const bh8*)(Wsw2 + l * 131072 +
                        (((w * 2 + i2) * 32 + ch * 4 + ks) * 64 + lane) * 8);
#pragma unroll
            for (int mt = 0; mt < 4; ++mt) {
                bh8 ffr[4];
#pragma unroll
                for (int ks = 0; ks < 4; ++ks)
                    ffr[ks] = *(const bh8*)&dst[mt * 16 + ln][ks * 32 + q * 8];
#pragma unroll
                for (int i2 = 0; i2 < 2; ++i2)
#pragma unroll
                    for (int ks = 0; ks < 4; ++ks)
                        f2a[i2][mt] = mfma16(w2fr[i2][ks], ffr[ks], f2a[i2][mt]);
            }
            // no trailing barrier: ping-pong buffered
        }
        // epilogue: + b2 + H residual, LN2 -> ACT (same inline-LN scheme)
        fx4 Cv2[2][4];
#pragma unroll
        for (int i2 = 0; i2 < 2; ++i2) {
            int n0 = (w * 2 + i2) * 16 + q * 4;
            fx4 bb4 = *(const fx4*)&b2p[l * 128 + n0];
#pragma unroll
            for (int mt = 0; mt < 4; ++mt) {
                us4 rv = *(const us4*)&Kb[mt * 16 + ln][n0];
#pragma unroll
                for (int r2 = 0; r2 < 4; ++r2)
                    Cv2[i2][mt][r2] = f2a[i2][mt][r2] + bb4[r2] + bu2f(rv[r2]);
            }
        }
#pragma unroll
        for (int mt = 0; mt < 4; ++mt) {
            float s = 0.f, v = 0.f;
#pragma unroll
            for (int i2 = 0; i2 < 2; ++i2)
#pragma unroll
                for (int r2 = 0; r2 < 4; ++r2) {
                    float a = Cv2[i2][mt][r2];
                    s += a; v = fmaf(a, a, v);
                }
            s += __shfl_xor(s, 16); v += __shfl_xor(v, 16);
            s += __shfl_xor(s, 32); v += __shfl_xor(v, 32);
            if (lane < 16) LNp2[mt * 16 + ln][w] = float2{s, v};
        }
        __syncthreads();
        {
            float mean4[4], inv4[4];
#pragma unroll
            for (int mt = 0; mt < 4; ++mt) {
                int row = mt * 16 + ln;
                float2 a0 = LNp2[row][0], a1 = LNp2[row][1];
                float2 a2 = LNp2[row][2], a3 = LNp2[row][3];
                float s = (a0.x + a1.x) + (a2.x + a3.x);
                float v = (a0.y + a1.y) + (a2.y + a3.y);
                float mean = s * (1.0f / 128.0f);
                mean4[mt] = mean;
                inv4[mt] = rsqrtf(v * (1.0f / 128.0f) - mean * mean + 1e-5f);
            }
#pragma unroll
            for (int i2 = 0; i2 < 2; ++i2) {
                int n0 = (w * 2 + i2) * 16 + q * 4;
                fx4 gg = *(const fx4*)&ln2g[l * 128 + n0];
                fx4 be = *(const fx4*)&ln2b[l * 128 + n0];
#pragma unroll
                for (int mt = 0; mt < 4; ++mt) {
                    us4 o;
#pragma unroll
                    for (int r2 = 0; r2 < 4; ++r2)
                        o[r2] = f2b((Cv2[i2][mt][r2] - mean4[mt]) * inv4[mt] * gg[r2] + be[r2]);
                    *(us4*)&ACT[mt * 16 + ln][n0] = o;
                }
            }
        }
        __syncthreads();
    }

    // ============ head partial dot: wave w handles batch bbase + w =========
    {
        int bg = bbase + w;
        float part = 0.f;
        int srow = lane >> 2, c0 = (lane & 3) * 32;
#pragma unroll
        for (int i = 0; i < 4; ++i) {
            bh8 av = *(const bh8*)&ACT[w * 16 + srow][c0 + i * 8];
            int fl = srow * 128 + c0 + i * 8;
#pragma unroll
            for (int e = 0; e < 8; ++e)
                part = fmaf(bu2f((unsigned short)av[e]), Wf[fl + e], part);
        }
        if (lane < GCN_SZ)
            part = fmaf(gcn[(size_t)bg * GCN_SZ + lane], Wf[2048 + lane], part);
#pragma unroll
        for (int off = 32; off; off >>= 1) part += __shfl_xor(part, off);
        if (lane == 0) acc1[bg] = part;
    }
}

// One wave per batch row: dot(num[b], wnc) + acc1[b] + C1 -> sigmoid.
__global__ __launch_bounds__(256) void final_fast(
    const float* __restrict__ num, const float* __restrict__ cvec,
    const float* __restrict__ acc1, float* __restrict__ out)
{
    __shared__ float wv[104];
    const int t = threadIdx.x;
    if (t < 104) wv[t] = cvec[t];
    __syncthreads();
    const int w = t >> 6, lane = t & 63;
    const int b = blockIdx.x * 4 + w;
    const float* nb = num + (size_t)b * NUMF_SZ;
    float part = nb[lane] * wv[lane];
    if (lane < NUMF_SZ - 64) part += nb[64 + lane] * wv[64 + lane];
#pragma unroll
    for (int o = 32; o; o >>= 1) part += __shfl_xor(part, o);
    if (lane == 0)
        out[b] = 1.0f / (1.0f + __expf(-(acc1[b] + part + wv[103])));
}

extern "C" void kernel_launch(void* const* d_in, const int* in_sizes, int n_in,
                              void* d_out, int out_size, void* d_ws, size_t ws_size,
                              hipStream_t stream)
{
    const float* x    = (const float*)d_in[0];
    const float* gcn  = (const float*)d_in[1];
    const float* num  = (const float*)d_in[2];
    const float* Wq   = (const float*)d_in[3];
    const float* bq   = (const float*)d_in[4];
    const float* Wk   = (const float*)d_in[5];
    const float* bk   = (const float*)d_in[6];
    const float* Wv   = (const float*)d_in[7];
    const float* bv   = (const float*)d_in[8];
    const float* Wo   = (const float*)d_in[9];
    const float* bo   = (const float*)d_in[10];
    const float* ln1g = (const float*)d_in[11];
    const float* ln1b = (const float*)d_in[12];
    const float* W1   = (const float*)d_in[13];
    const float* b1   = (const float*)d_in[14];
    const float* W2   = (const float*)d_in[15];
    const float* b2p  = (const float*)d_in[16];
    const float* ln2g = (const float*)d_in[17];
    const float* ln2b = (const float*)d_in[18];
    const float* Wn   = (const float*)d_in[19];
    const float* bnum = (const float*)d_in[20];
    const float* bng  = (const float*)d_in[21];
    const float* bnb  = (const float*)d_in[22];
    const float* Wf   = (const float*)d_in[23];
    const float* bfin = (const float*)d_in[24];

    // ws: acc1 (8192 f32) | ssum(128) | ssq(128) | cnt(1) | pad to 40960
    //     | swizzled bf16 weights | PE (8 KB) | cvec (104 f32)
    float* acc1 = (float*)d_ws;
    float* ssum = acc1 + B_SZ;
    float* ssq  = ssum + 128;
    unsigned int* cnt = (unsigned int*)(ssq + 128);
    unsigned short* wb = (unsigned short*)((char*)d_ws + 40960);
    unsigned short* WswQ = wb;
    unsigned short* WswK = wb + 32768;
    unsigned short* WswV = wb + 65536;
    unsigned short* WswO = wb + 98304;
    unsigned short* Wsw1 = wb + 131072;
    unsigned short* Wsw2 = wb + 393216;
    float* PEt = (float*)((char*)d_ws + 40960 + 1310720);
    float* cvec = (float*)((char*)d_ws + 40960 + 1310720 + 8192);

    hipMemsetAsync(ssum, 0, 257 * sizeof(float), stream);
    prep_weights<<<1024, 256, 0, stream>>>(Wq, Wk, Wv, Wo, W1, W2,
        WswQ, WswK, WswV, WswO, Wsw1, Wsw2, PEt);
    encoder_fused<<<NBLK + SBLK, 256, 0, stream>>>(x, gcn, bq, bk, bv, bo,
        ln1g, ln1b, b1, b2p, ln2g, ln2b, Wf,
        WswQ, WswK, WswV, WswO, Wsw1, Wsw2, PEt,
        num, Wn, bnum, ssum, ssq, cnt, bng, bnb, bfin, cvec, acc1);
    final_fast<<<B_SZ / 4, 256, 0, stream>>>(num, cvec, acc1, (float*)d_out);
}